// Round 4
// baseline (114.238 us; speedup 1.0000x reference)
//
#include <hip/hip_runtime.h>

#define LSZ 512
#define CCH 4
#define NLAY 4
#define TILE 64
#define HALO 8
#define RG 80        // region size = TILE + 2*HALO
#define RG2 40       // float2 row pitch

typedef float v2f __attribute__((ext_vector_type(2)));

// Packed fp32 math (CDNA2+ VOP3P). Component-wise IEEE fp32, so the
// bitwise-symmetry argument is unchanged vs scalar.
__device__ __forceinline__ v2f pk_add(v2f a, v2f b) {
    v2f d; asm("v_pk_add_f32 %0, %1, %2" : "=v"(d) : "v"(a), "v"(b)); return d;
}
__device__ __forceinline__ v2f pk_mul(v2f a, v2f b) {
    v2f d; asm("v_pk_mul_f32 %0, %1, %2" : "=v"(d) : "v"(a), "v"(b)); return d;
}
__device__ __forceinline__ v2f pk_fma(v2f a, v2f b, v2f c) {
    v2f d; asm("v_pk_fma_f32 %0, %1, %2, %3" : "=v"(d) : "v"(a), "v"(b), "v"(c)); return d;
}

__device__ __forceinline__ v2f celu2(v2f y) {
    v2f r;
    r.x = y.x >= 0.0f ? y.x : __expf(y.x) - 1.0f;
    r.y = y.y >= 0.0f ? y.y : __expf(y.y) - 1.0f;
    return r;
}

// aligned 8B LDS load (caller guarantees even float index)
__device__ __forceinline__ v2f ld2(const float* p) { return *(const v2f*)p; }
// unaligned (odd index) pair load -> ds_read2_b32
__device__ __forceinline__ v2f ld2u(const float* p) {
    v2f r; r.x = p[0]; r.y = p[1]; return r;
}

// One workgroup per (b, c, upper-triangular 64x64 tile).
// Builds g from n on the fly, runs 4 stencil layers IN PLACE in one 80x80 LDS
// buffer (outputs staged in regs between two barriers), then reduces the 127
// cyclic diagonals into sep via atomics. Tiles with ti>tj are skipped; their
// contribution is the mirror bin (512-r) — valid because x stays bitwise
// symmetric (all transpose-paired sums commute exactly).
__global__ __launch_bounds__(256, 4) void stencil_kernel(
    const float* __restrict__ nn,
    const float* __restrict__ w_self,
    const float* __restrict__ w_nbr,
    float* __restrict__ sep)
{
    __shared__ __align__(16) float buf[RG * RG];
    __shared__ float nrow[RG][3];
    __shared__ float ncol[RG][3];

    const int tid = threadIdx.x;
    const int bid = blockIdx.x;
    const int img = bid / 36;           // 36 upper-tri tiles per (b,c) image
    int t = bid - img * 36;
    const int b = img >> 2;
    const int c = img & 3;
    int ti = 0;
    while (t >= 8 - ti) { t -= 8 - ti; ti++; }
    const int tj = ti + t;
    const int gi0 = ti * TILE;
    const int gj0 = tj * TILE;
    const int dd = (gj0 - gi0) & (LSZ - 1);   // diag when (i-j-dd) % 512 == 0
    // Only these tiles can intersect a cyclic-diagonal zero line within the
    // 80x80 halo region (|i-j| <= 78 in region coords):
    const bool tile_masked = (dd == 0) || (dd == 64) || (dd == 448);

    // ---- load n rows & cols (with halo, cyclic wrap) ----
    for (int u = tid; u < RG * 3 * 2; u += 256) {
        int which = u >= RG * 3;
        int v = which ? u - RG * 3 : u;
        int rr = v / 3, d = v - 3 * rr;
        int base = which ? gj0 : gi0;
        int gl = (base - HALO + rr) & (LSZ - 1);
        float val = nn[(b * LSZ + gl) * 3 + d];
        if (which) ncol[rr][d] = val; else nrow[rr][d] = val;
    }

    // ---- per-site precompute: anchor offset, ring-min, diag-mask code ----
    // site = 2x2 block at even (i, j); 1600 sites, 7 slots/thread
    int ofs[7];   // i*RG + j, or -1 for empty slot
    int ring[7];  // min(i, 78-i, j, 78-j); active at layer ell iff ring >= 2*(ell+1)
    int ew[7];    // (i-j-dd+1) & 511: 1 -> zero (0,0),(1,1); 2 -> (0,1); 0 -> (1,0)
#pragma unroll
    for (int it = 0; it < 7; it++) {
        int g = tid + 256 * it;
        if (g < 1600) {
            int gi2 = g / RG2;
            int i = 2 * gi2, j = 2 * (g - RG2 * gi2);
            ofs[it]  = i * RG + j;
            ring[it] = min(min(i, 78 - i), min(j, 78 - j));
            ew[it]   = (i - j - dd + 1) & 511;
        } else { ofs[it] = -1; ring[it] = -1; ew[it] = 99; }
    }
    __syncthreads();

    // ---- build g (Gram matrix, zero diagonal), 2x2 blocks ----
#pragma unroll
    for (int it = 0; it < 7; it++) {
        if (ofs[it] < 0) continue;
        int i = ofs[it] / RG, j = ofs[it] - i * RG;
        float a00 = nrow[i][0],   a01 = nrow[i][1],   a02 = nrow[i][2];
        float a10 = nrow[i+1][0], a11 = nrow[i+1][1], a12 = nrow[i+1][2];
        float c00 = ncol[j][0],   c01 = ncol[j][1],   c02 = ncol[j][2];
        float c10 = ncol[j+1][0], c11 = ncol[j+1][1], c12 = ncol[j+1][2];
        float g00 = a00*c00 + a01*c01 + a02*c02;
        float g01 = a00*c10 + a01*c11 + a02*c12;
        float g10 = a10*c00 + a11*c01 + a12*c02;
        float g11 = a10*c10 + a11*c11 + a12*c12;
        if (tile_masked) {
            if (ew[it] == 1) { g00 = 0.0f; g11 = 0.0f; }
            if (ew[it] == 2)   g01 = 0.0f;
            if (ew[it] == 0)   g10 = 0.0f;
        }
        *(v2f*)&buf[ofs[it]]      = (v2f){g00, g01};
        *(v2f*)&buf[ofs[it] + RG] = (v2f){g10, g11};
    }
    __syncthreads();

    // ---- 4 stencil layers, in place: compute->regs, barrier, write, barrier ----
    for (int ell = 0; ell < NLAY; ell++) {
        const float ws  = w_self[c * NLAY + ell];
        const float wn1 = w_nbr[(c * NLAY + ell) * 2 + 0];
        const float wn2 = w_nbr[(c * NLAY + ell) * 2 + 1];
        const v2f ws2 = (v2f){ws,  ws};
        const v2f w12 = (v2f){wn1, wn1};
        const v2f w22 = (v2f){wn2, wn2};
        const int pad = 2 * (ell + 1);
        v2f o0[7], o1[7];
#pragma unroll
        for (int it = 0; it < 7; it++) {
            if (ring[it] < pad) continue;
            const float* P = buf + ofs[it];
            // vertical column pairs (all 8B aligned: even i*RG + even j)
            v2f cm2 = ld2(P - 2*RG);
            v2f cm1 = ld2(P -   RG);
            v2f c0  = ld2(P);
            v2f cp1 = ld2(P +   RG);
            v2f cp2 = ld2(P + 2*RG);
            v2f cp3 = ld2(P + 3*RG);
            // horizontal pairs, row i
            v2f L2a = ld2 (P - 2);      // (j-2, j-1)
            v2f L1a = ld2u(P - 1);      // (j-1, j  )
            v2f R1a = ld2u(P + 1);      // (j+1, j+2)
            v2f R2a = ld2 (P + 2);      // (j+2, j+3)
            // horizontal pairs, row i+1
            v2f L2b = ld2 (P + RG - 2);
            v2f L1b = ld2u(P + RG - 1);
            v2f R1b = ld2u(P + RG + 1);
            v2f R2b = ld2 (P + RG + 2);
            // row i outputs (cols j, j+1):
            //   s1 = (left+right) + (up+down); transpose site computes
            //   (up+down)+(left+right) with identical operands -> bitwise equal
            v2f s1a = pk_add(pk_add(L1a, R1a), pk_add(cm1, cp1));
            v2f s2a = pk_add(pk_add(L2a, R2a), pk_add(cm2, cp2));
            v2f ya  = pk_fma(ws2, c0,  pk_fma(w12, s1a, pk_mul(w22, s2a)));
            // row i+1 outputs:
            v2f s1b = pk_add(pk_add(L1b, R1b), pk_add(c0,  cp2));
            v2f s2b = pk_add(pk_add(L2b, R2b), pk_add(cm1, cp3));
            v2f yb  = pk_fma(ws2, cp1, pk_fma(w12, s1b, pk_mul(w22, s2b)));
            v2f xa = pk_add(c0,  celu2(ya));
            v2f xb = pk_add(cp1, celu2(yb));
            if (tile_masked) {
                if (ew[it] == 1) { xa.x = 0.0f; xb.y = 0.0f; }
                if (ew[it] == 2)   xa.y = 0.0f;
                if (ew[it] == 0)   xb.x = 0.0f;
            }
            o0[it] = xa;
            o1[it] = xb;
        }
        __syncthreads();
#pragma unroll
        for (int it = 0; it < 7; it++) {
            if (ring[it] < pad) continue;
            *(v2f*)&buf[ofs[it]]      = o0[it];
            *(v2f*)&buf[ofs[it] + RG] = o1[it];
        }
        __syncthreads();
    }
    // final x is in buf (core = region [8,72)^2)

    // ---- cyclic-diagonal reduction: 127 diagonals, 2 threads each ----
    if (tid < 254) {
        int dt = tid >> 1;
        int half = tid & 1;
        int delta = dt - 63;                 // j - i in [-63, 63]
        int ad = delta < 0 ? -delta : delta;
        int Nd = 64 - ad;
        int i0 = 8 + (delta < 0 ? -delta : 0);
        int base = i0 * RG + (i0 + delta);
        float s = 0.0f;
        for (int k = half; k < Nd; k += 2)
            s += buf[base + k * (RG + 1)];
        s += __shfl_xor(s, 1);
        if (half == 0) {
            int r = (gj0 - gi0 + delta) & (LSZ - 1);
            float* sp = sep + (b * CCH + c) * LSZ;
            atomicAdd(sp + r, s);
            if (ti != tj)  // mirror contribution for the skipped transpose tile
                atomicAdd(sp + ((LSZ - r) & (LSZ - 1)), s);
        }
    }
}

// MLP stage 1: partial[b][mp][k] = sep[b, mp*128:(mp+1)*128] . W1[slice, k]
__global__ __launch_bounds__(256) void mlp1_kernel(
    const float* __restrict__ sep,
    const float* __restrict__ W1,
    float* __restrict__ partial)
{
    const int b  = blockIdx.x >> 4;
    const int mp = blockIdx.x & 15;
    const int k  = threadIdx.x;
    const float* sv = sep + b * 2048 + mp * 128;
    const float* w  = W1 + mp * 128 * 256 + k;
    float a0 = 0, a1 = 0, a2 = 0, a3 = 0;
#pragma unroll 8
    for (int m = 0; m < 128; m += 4) {
        a0 += sv[m]     * w[(m)     * 256];
        a1 += sv[m + 1] * w[(m + 1) * 256];
        a2 += sv[m + 2] * w[(m + 2) * 256];
        a3 += sv[m + 3] * w[(m + 3) * 256];
    }
    partial[blockIdx.x * 256 + k] = (a0 + a1) + (a2 + a3);
}

// MLP stage 2: h[k] = celu(sum_p partial + b1) in double; y = h.W2 + b2;
// out = exp(-y). Deterministic reduction.
__global__ __launch_bounds__(256) void mlp2_kernel(
    const float* __restrict__ partial,
    const float* __restrict__ b1,
    const float* __restrict__ W2,
    const float* __restrict__ b2,
    float* __restrict__ out)
{
    __shared__ double red[4];
    const int b = blockIdx.x;
    const int k = threadIdx.x;
    double s = 0;
#pragma unroll
    for (int p = 0; p < 16; p++)
        s += (double)partial[(b * 16 + p) * 256 + k];
    s += (double)b1[k];
    s = s >= 0.0 ? s : exp(s) - 1.0;          // celu
    double q = s * (double)W2[k];
    for (int off = 32; off >= 1; off >>= 1) q += __shfl_down(q, off);
    if ((k & 63) == 0) red[k >> 6] = q;
    __syncthreads();
    if (k == 0) {
        double y = ((red[0] + red[1]) + (red[2] + red[3])) + (double)b2[0];
        out[b] = (float)exp(-y);
    }
}

extern "C" void kernel_launch(void* const* d_in, const int* in_sizes, int n_in,
                              void* d_out, int out_size, void* d_ws, size_t ws_size,
                              hipStream_t stream) {
    const float* nn     = (const float*)d_in[0];
    const float* w_self = (const float*)d_in[1];
    const float* w_nbr  = (const float*)d_in[2];
    const float* W1     = (const float*)d_in[3];
    const float* b1     = (const float*)d_in[4];
    const float* W2     = (const float*)d_in[5];
    const float* b2     = (const float*)d_in[6];
    float* out = (float*)d_out;
    float* sep     = (float*)d_ws;                                  // 128 KB
    float* partial = (float*)((char*)d_ws + 16 * CCH * LSZ * sizeof(float)); // 256 KB

    hipMemsetAsync(sep, 0, 16 * CCH * LSZ * sizeof(float), stream);
    stencil_kernel<<<64 * 36, 256, 0, stream>>>(nn, w_self, w_nbr, sep);
    mlp1_kernel<<<256, 256, 0, stream>>>(sep, W1, partial);
    mlp2_kernel<<<16, 256, 0, stream>>>(partial, b1, W2, b2, out);
}

// Round 5
// 114.065 us; speedup vs baseline: 1.0015x; 1.0015x over previous
//
#include <hip/hip_runtime.h>

#define LSZ 512
#define CCH 4
#define NLAY 4
#define TILE 64
#define HALO 8
#define RG 80        // region size = TILE + 2*HALO
#define RG2 40       // float2 row pitch

typedef float v2f __attribute__((ext_vector_type(2)));

// Packed fp32 math (VOP3P). Component-wise IEEE fp32, so the
// bitwise-symmetry argument is unchanged vs scalar.
__device__ __forceinline__ v2f pk_add(v2f a, v2f b) {
    v2f d; asm("v_pk_add_f32 %0, %1, %2" : "=v"(d) : "v"(a), "v"(b)); return d;
}
__device__ __forceinline__ v2f pk_mul(v2f a, v2f b) {
    v2f d; asm("v_pk_mul_f32 %0, %1, %2" : "=v"(d) : "v"(a), "v"(b)); return d;
}
__device__ __forceinline__ v2f pk_fma(v2f a, v2f b, v2f c) {
    v2f d; asm("v_pk_fma_f32 %0, %1, %2, %3" : "=v"(d) : "v"(a), "v"(b), "v"(c)); return d;
}

__device__ __forceinline__ v2f celu2(v2f y) {
    v2f r;
    r.x = y.x >= 0.0f ? y.x : __expf(y.x) - 1.0f;
    r.y = y.y >= 0.0f ? y.y : __expf(y.y) - 1.0f;
    return r;
}

// aligned 8B LDS load (caller guarantees even float index)
__device__ __forceinline__ v2f ld2(const float* p) { return *(const v2f*)p; }
// unaligned (odd index) pair load -> ds_read2_b32
__device__ __forceinline__ v2f ld2u(const float* p) {
    v2f r; r.x = p[0]; r.y = p[1]; return r;
}

// One workgroup per (b, c, upper-triangular 64x64 tile).  (UNCHANGED from R4 —
// control for this round's experiment; known LDS-pipe-bound at ~47 us.)
__global__ __launch_bounds__(256, 4) void stencil_kernel(
    const float* __restrict__ nn,
    const float* __restrict__ w_self,
    const float* __restrict__ w_nbr,
    float* __restrict__ sep)
{
    __shared__ __align__(16) float buf[RG * RG];
    __shared__ float nrow[RG][3];
    __shared__ float ncol[RG][3];

    const int tid = threadIdx.x;
    const int bid = blockIdx.x;
    const int img = bid / 36;           // 36 upper-tri tiles per (b,c) image
    int t = bid - img * 36;
    const int b = img >> 2;
    const int c = img & 3;
    int ti = 0;
    while (t >= 8 - ti) { t -= 8 - ti; ti++; }
    const int tj = ti + t;
    const int gi0 = ti * TILE;
    const int gj0 = tj * TILE;
    const int dd = (gj0 - gi0) & (LSZ - 1);   // diag when (i-j-dd) % 512 == 0
    const bool tile_masked = (dd == 0) || (dd == 64) || (dd == 448);

    // ---- load n rows & cols (with halo, cyclic wrap) ----
    for (int u = tid; u < RG * 3 * 2; u += 256) {
        int which = u >= RG * 3;
        int v = which ? u - RG * 3 : u;
        int rr = v / 3, d = v - 3 * rr;
        int base = which ? gj0 : gi0;
        int gl = (base - HALO + rr) & (LSZ - 1);
        float val = nn[(b * LSZ + gl) * 3 + d];
        if (which) ncol[rr][d] = val; else nrow[rr][d] = val;
    }

    // ---- per-site precompute: anchor offset, ring-min, diag-mask code ----
    int ofs[7];   // i*RG + j, or -1 for empty slot
    int ring[7];  // min(i, 78-i, j, 78-j); active at layer ell iff ring >= 2*(ell+1)
    int ew[7];    // (i-j-dd+1) & 511: 1 -> zero (0,0),(1,1); 2 -> (0,1); 0 -> (1,0)
#pragma unroll
    for (int it = 0; it < 7; it++) {
        int g = tid + 256 * it;
        if (g < 1600) {
            int gi2 = g / RG2;
            int i = 2 * gi2, j = 2 * (g - RG2 * gi2);
            ofs[it]  = i * RG + j;
            ring[it] = min(min(i, 78 - i), min(j, 78 - j));
            ew[it]   = (i - j - dd + 1) & 511;
        } else { ofs[it] = -1; ring[it] = -1; ew[it] = 99; }
    }
    __syncthreads();

    // ---- build g (Gram matrix, zero diagonal), 2x2 blocks ----
#pragma unroll
    for (int it = 0; it < 7; it++) {
        if (ofs[it] < 0) continue;
        int i = ofs[it] / RG, j = ofs[it] - i * RG;
        float a00 = nrow[i][0],   a01 = nrow[i][1],   a02 = nrow[i][2];
        float a10 = nrow[i+1][0], a11 = nrow[i+1][1], a12 = nrow[i+1][2];
        float c00 = ncol[j][0],   c01 = ncol[j][1],   c02 = ncol[j][2];
        float c10 = ncol[j+1][0], c11 = ncol[j+1][1], c12 = ncol[j+1][2];
        float g00 = a00*c00 + a01*c01 + a02*c02;
        float g01 = a00*c10 + a01*c11 + a02*c12;
        float g10 = a10*c00 + a11*c01 + a12*c02;
        float g11 = a10*c10 + a11*c11 + a12*c12;
        if (tile_masked) {
            if (ew[it] == 1) { g00 = 0.0f; g11 = 0.0f; }
            if (ew[it] == 2)   g01 = 0.0f;
            if (ew[it] == 0)   g10 = 0.0f;
        }
        *(v2f*)&buf[ofs[it]]      = (v2f){g00, g01};
        *(v2f*)&buf[ofs[it] + RG] = (v2f){g10, g11};
    }
    __syncthreads();

    // ---- 4 stencil layers, in place: compute->regs, barrier, write, barrier ----
    for (int ell = 0; ell < NLAY; ell++) {
        const float ws  = w_self[c * NLAY + ell];
        const float wn1 = w_nbr[(c * NLAY + ell) * 2 + 0];
        const float wn2 = w_nbr[(c * NLAY + ell) * 2 + 1];
        const v2f ws2 = (v2f){ws,  ws};
        const v2f w12 = (v2f){wn1, wn1};
        const v2f w22 = (v2f){wn2, wn2};
        const int pad = 2 * (ell + 1);
        v2f o0[7], o1[7];
#pragma unroll
        for (int it = 0; it < 7; it++) {
            if (ring[it] < pad) continue;
            const float* P = buf + ofs[it];
            v2f cm2 = ld2(P - 2*RG);
            v2f cm1 = ld2(P -   RG);
            v2f c0  = ld2(P);
            v2f cp1 = ld2(P +   RG);
            v2f cp2 = ld2(P + 2*RG);
            v2f cp3 = ld2(P + 3*RG);
            v2f L2a = ld2 (P - 2);
            v2f L1a = ld2u(P - 1);
            v2f R1a = ld2u(P + 1);
            v2f R2a = ld2 (P + 2);
            v2f L2b = ld2 (P + RG - 2);
            v2f L1b = ld2u(P + RG - 1);
            v2f R1b = ld2u(P + RG + 1);
            v2f R2b = ld2 (P + RG + 2);
            v2f s1a = pk_add(pk_add(L1a, R1a), pk_add(cm1, cp1));
            v2f s2a = pk_add(pk_add(L2a, R2a), pk_add(cm2, cp2));
            v2f ya  = pk_fma(ws2, c0,  pk_fma(w12, s1a, pk_mul(w22, s2a)));
            v2f s1b = pk_add(pk_add(L1b, R1b), pk_add(c0,  cp2));
            v2f s2b = pk_add(pk_add(L2b, R2b), pk_add(cm1, cp3));
            v2f yb  = pk_fma(ws2, cp1, pk_fma(w12, s1b, pk_mul(w22, s2b)));
            v2f xa = pk_add(c0,  celu2(ya));
            v2f xb = pk_add(cp1, celu2(yb));
            if (tile_masked) {
                if (ew[it] == 1) { xa.x = 0.0f; xb.y = 0.0f; }
                if (ew[it] == 2)   xa.y = 0.0f;
                if (ew[it] == 0)   xb.x = 0.0f;
            }
            o0[it] = xa;
            o1[it] = xb;
        }
        __syncthreads();
#pragma unroll
        for (int it = 0; it < 7; it++) {
            if (ring[it] < pad) continue;
            *(v2f*)&buf[ofs[it]]      = o0[it];
            *(v2f*)&buf[ofs[it] + RG] = o1[it];
        }
        __syncthreads();
    }

    // ---- cyclic-diagonal reduction: 127 diagonals, 2 threads each ----
    if (tid < 254) {
        int dt = tid >> 1;
        int half = tid & 1;
        int delta = dt - 63;                 // j - i in [-63, 63]
        int ad = delta < 0 ? -delta : delta;
        int Nd = 64 - ad;
        int i0 = 8 + (delta < 0 ? -delta : 0);
        int base = i0 * RG + (i0 + delta);
        float s = 0.0f;
        for (int k = half; k < Nd; k += 2)
            s += buf[base + k * (RG + 1)];
        s += __shfl_xor(s, 1);
        if (half == 0) {
            int r = (gj0 - gi0 + delta) & (LSZ - 1);
            float* sp = sep + (b * CCH + c) * LSZ;
            atomicAdd(sp + r, s);
            if (ti != tj)
                atomicAdd(sp + ((LSZ - r) & (LSZ - 1)), s);
        }
    }
}

// MLP stage 1 (rebuilt): partial[(b*32+ms)*256+k] = sep[b, ms*64:(ms+1)*64] . W1[slice, k]
// Grid 512 = 16 b x 32 m-slices (8 waves/CU). Block 256 = 64 kq x 4 mq.
// Thread (kq,mq): owns k = 4kq..4kq+3, m-range = ms*64+mq*16 .. +16.
// 16 independent float4 W1 loads per thread (coalesced 1KB/wave, fully
// vmcnt-pipelined); sep reads wave-uniform (scalar). LDS-reduce the 4 mq
// subgroups -> one partial per (b,ms). Deterministic fixed-order sums.
__global__ __launch_bounds__(256) void mlp1_kernel(
    const float* __restrict__ sep,
    const float* __restrict__ W1,
    float* __restrict__ partial)
{
    __shared__ float4 red[4][64];
    const int b  = blockIdx.x >> 5;
    const int ms = blockIdx.x & 31;
    const int kq = threadIdx.x & 63;
    const int mq = threadIdx.x >> 6;
    const int m0 = ms * 64 + mq * 16;
    const float* sv = sep + b * 2048 + m0;
    const float* w  = W1 + m0 * 256 + kq * 4;
    float4 a0 = {0,0,0,0}, a1 = {0,0,0,0};
#pragma unroll
    for (int m = 0; m < 16; m += 2) {
        float4 w0 = *(const float4*)(w + (m)     * 256);
        float4 w1 = *(const float4*)(w + (m + 1) * 256);
        float s0 = sv[m], s1 = sv[m + 1];
        a0.x += s0 * w0.x; a0.y += s0 * w0.y; a0.z += s0 * w0.z; a0.w += s0 * w0.w;
        a1.x += s1 * w1.x; a1.y += s1 * w1.y; a1.z += s1 * w1.z; a1.w += s1 * w1.w;
    }
    float4 a;
    a.x = a0.x + a1.x; a.y = a0.y + a1.y; a.z = a0.z + a1.z; a.w = a0.w + a1.w;
    red[mq][kq] = a;
    __syncthreads();
    if (mq == 0) {
        float4 r0 = red[0][kq], r1 = red[1][kq], r2 = red[2][kq], r3 = red[3][kq];
        float4 o;
        o.x = (r0.x + r1.x) + (r2.x + r3.x);
        o.y = (r0.y + r1.y) + (r2.y + r3.y);
        o.z = (r0.z + r1.z) + (r2.z + r3.z);
        o.w = (r0.w + r1.w) + (r2.w + r3.w);
        *(float4*)&partial[(b * 32 + ms) * 256 + kq * 4] = o;
    }
}

// MLP stage 2: h[k] = celu(sum_ms partial + b1) in double; y = h.W2 + b2;
// out = exp(-y). 32 independent coalesced loads per thread, deterministic.
__global__ __launch_bounds__(256) void mlp2_kernel(
    const float* __restrict__ partial,
    const float* __restrict__ b1,
    const float* __restrict__ W2,
    const float* __restrict__ b2,
    float* __restrict__ out)
{
    __shared__ double red[4];
    const int b = blockIdx.x;
    const int k = threadIdx.x;
    double s = 0;
#pragma unroll
    for (int p = 0; p < 32; p++)
        s += (double)partial[(b * 32 + p) * 256 + k];
    s += (double)b1[k];
    s = s >= 0.0 ? s : exp(s) - 1.0;          // celu
    double q = s * (double)W2[k];
    for (int off = 32; off >= 1; off >>= 1) q += __shfl_down(q, off);
    if ((k & 63) == 0) red[k >> 6] = q;
    __syncthreads();
    if (k == 0) {
        double y = ((red[0] + red[1]) + (red[2] + red[3])) + (double)b2[0];
        out[b] = (float)exp(-y);
    }
}

extern "C" void kernel_launch(void* const* d_in, const int* in_sizes, int n_in,
                              void* d_out, int out_size, void* d_ws, size_t ws_size,
                              hipStream_t stream) {
    const float* nn     = (const float*)d_in[0];
    const float* w_self = (const float*)d_in[1];
    const float* w_nbr  = (const float*)d_in[2];
    const float* W1     = (const float*)d_in[3];
    const float* b1     = (const float*)d_in[4];
    const float* W2     = (const float*)d_in[5];
    const float* b2     = (const float*)d_in[6];
    float* out = (float*)d_out;
    float* sep     = (float*)d_ws;                                  // 128 KB
    float* partial = (float*)((char*)d_ws + 16 * CCH * LSZ * sizeof(float)); // 512 KB

    hipMemsetAsync(sep, 0, 16 * CCH * LSZ * sizeof(float), stream);
    stencil_kernel<<<64 * 36, 256, 0, stream>>>(nn, w_self, w_nbr, sep);
    mlp1_kernel<<<512, 256, 0, stream>>>(sep, W1, partial);
    mlp2_kernel<<<16, 256, 0, stream>>>(partial, b1, W2, b2, out);
}